// Round 7
// baseline (909.905 us; speedup 1.0000x reference)
//
#include <hip/hip_runtime.h>
#include <hip/hip_fp16.h>
#include <math.h>

// GCN forward: GCNConv(6->4, self-loops, sym-norm) -> tanh -> mean-pool -> fc1+relu -> fc3
// agg[c] = dinv[c] * ( sum_{edges r->c} p[r] + p[c] ) + conv_b, p[i] = (W x[i]) * dinv[i]
//
// R6/R7 theory: ~13 cy per divergent L1-missing lane-transaction, serialized per CU
// (R3/R4/R5 k_acc all ~345us regardless of structure; R1 scatter = 64M lanes ~30cy).
// Fix: NO random global accesses anywhere. Dual binning with value-carrying records:
//   binT (2B c_local recs) -> deg           [random work in LDS only]
//   node: p = (W x)*dinv -> fp16            [coalesced]
//   binS (4B (c<<10)|r_local recs by source partition)
//   attach: p-slice (fp8x4) in LDS, gather from LDS, counting-sort (val,cl) to target bins
//   accV: stream value records, ds_add LDS tile, partials -> tanh -> head
// R7: fix ext-vector accessors on cvt_pk_f32_fp8 result ([0]/[1], not .x/.y).

constexpr int NP = 1024;        // nodes per partition
constexpr int SHIFT = 10;
constexpr unsigned MASK = 1023;
constexpr int NPART_MAX = 512;  // scan width; P = ceil(500k/1024) = 489
constexpr int EPB = 8192;       // edges per binning block
constexpr int BINB = 512;       // binning block size
constexpr int BT = 512;
constexpr int SUBD = 4;         // deg-count chunks per partition
constexpr int SUBA = 4;         // attach chunks per source partition
constexpr int SUBV = 4;         // accumulate chunks per target partition
constexpr int CHMAX = 8704;     // max chunk (>= ceil(cap/SUBA))

struct alignas(8) Half4 { __half2 a, b; };
typedef float floatx2 __attribute__((ext_vector_type(2)));

// ---------------- pass 1: bin by target partition, 2B records (c_local) ----------------

__global__ __launch_bounds__(BINB) void k_binT2(const int* __restrict__ col, int E,
                                                int P, int cap, int* __restrict__ cursorT,
                                                unsigned short* __restrict__ binT) {
    __shared__ unsigned short lbuf[EPB];    // 16 KB
    __shared__ int lcount[NPART_MAX];
    __shared__ int lbase[NPART_MAX];
    __shared__ int gbase[NPART_MAX];
    __shared__ int lpos[NPART_MAX];
    __shared__ int sc[NPART_MAX];

    int t = threadIdx.x;
    int start = blockIdx.x * EPB;
    int end = min(start + EPB, E);
    bool full = (end - start) == EPB;

    lcount[t] = 0; lpos[t] = 0;
    __syncthreads();

    if (full) {
        const int4* c4 = (const int4*)(col + start);
#pragma unroll
        for (int i = 0; i < EPB / 4 / BINB; ++i) {
            int4 c = c4[t + i * BINB];
            atomicAdd(&lcount[c.x >> SHIFT], 1);
            atomicAdd(&lcount[c.y >> SHIFT], 1);
            atomicAdd(&lcount[c.z >> SHIFT], 1);
            atomicAdd(&lcount[c.w >> SHIFT], 1);
        }
    } else {
        for (int e = start + t; e < end; e += BINB)
            atomicAdd(&lcount[col[e] >> SHIFT], 1);
    }
    __syncthreads();

    sc[t] = lcount[t];
    __syncthreads();
    for (int off = 1; off < NPART_MAX; off <<= 1) {
        int v = (t >= off) ? sc[t - off] : 0;
        __syncthreads();
        sc[t] += v;
        __syncthreads();
    }
    lbase[t] = sc[t] - lcount[t];
    if (t < P) {
        int c = lcount[t];
        gbase[t] = (c > 0) ? atomicAdd(&cursorT[t], c) : 0;
    }
    __syncthreads();

    if (full) {
        const int4* c4 = (const int4*)(col + start);
#pragma unroll
        for (int i = 0; i < EPB / 4 / BINB; ++i) {
            int4 c = c4[t + i * BINB];
            int part, slot;
            part = c.x >> SHIFT; slot = atomicAdd(&lpos[part], 1);
            lbuf[lbase[part] + slot] = (unsigned short)(c.x & MASK);
            part = c.y >> SHIFT; slot = atomicAdd(&lpos[part], 1);
            lbuf[lbase[part] + slot] = (unsigned short)(c.y & MASK);
            part = c.z >> SHIFT; slot = atomicAdd(&lpos[part], 1);
            lbuf[lbase[part] + slot] = (unsigned short)(c.z & MASK);
            part = c.w >> SHIFT; slot = atomicAdd(&lpos[part], 1);
            lbuf[lbase[part] + slot] = (unsigned short)(c.w & MASK);
        }
    } else {
        for (int e = start + t; e < end; e += BINB) {
            int c = col[e];
            int part = c >> SHIFT;
            int slot = atomicAdd(&lpos[part], 1);
            lbuf[lbase[part] + slot] = (unsigned short)(c & MASK);
        }
    }
    __syncthreads();

    int lane = t & 63;
    int wave = t >> 6;
    const int nwaves = BINB / 64;
    for (int part = wave; part < P; part += nwaves) {
        int cnt = lcount[part];
        if (cnt == 0) continue;
        int lb = lbase[part];
        int gb = gbase[part];
        unsigned short* dst = binT + (size_t)part * cap;
        for (int j = lane; j < cnt; j += 64) {
            int slot = gb + j;
            if (slot < cap) dst[slot] = lbuf[lb + j];
        }
    }
}

// ---------------- pass 2a: partial deg counts per (partition, chunk) ----------------

__global__ __launch_bounds__(BT) void k_degS(const unsigned short* __restrict__ binT,
                                             const int* __restrict__ cursorT, int cap,
                                             int* __restrict__ degpart) {
    __shared__ int degs[NP];
    int part = blockIdx.x >> 2;         // SUBD = 4
    int sub = blockIdx.x & 3;
    int tid = threadIdx.x;
    for (int i = tid; i < NP; i += BT) degs[i] = 0;
    __syncthreads();
    int cnt = min(cursorT[part], cap);
    int chunk = (cnt + SUBD - 1) / SUBD;
    int s = sub * chunk;
    int e = min(cnt, s + chunk);
    const unsigned short* bin = binT + (size_t)part * cap;
    for (int i = s + tid; i < e; i += BT)
        atomicAdd(&degs[bin[i]], 1);
    __syncthreads();
    int* dst = degpart + (size_t)blockIdx.x * NP;
    for (int i = tid; i < NP; i += BT) dst[i] = degs[i];
}

// ---------------- pass 2b: dinv + p (fp16x4) per node ----------------

__global__ __launch_bounds__(BT) void k_node2(const int* __restrict__ degpart,
                                              const float* __restrict__ x,
                                              const float* __restrict__ conv_w, int n,
                                              Half4* __restrict__ ph,
                                              float* __restrict__ dinvg) {
    __shared__ float w[24];
    int tid = threadIdx.x;
    if (tid < 24) w[tid] = conv_w[tid];
    __syncthreads();
    int i = blockIdx.x * BT + tid;
    if (i >= n) return;
    int part = i >> SHIFT;
    int local = i & MASK;
    const int* dp = degpart + (size_t)part * SUBD * NP + local;
    int deg = dp[0] + dp[NP] + dp[2 * NP] + dp[3 * NP];
    float dinv = rsqrtf((float)(deg + 1));      // +1 self-loop
    const float* xr = x + (size_t)i * 6;
    float2 a = *(const float2*)xr;
    float2 b = *(const float2*)(xr + 2);
    float2 cc = *(const float2*)(xr + 4);
    float xv[6] = {a.x, a.y, b.x, b.y, cc.x, cc.y};
    float h0 = 0.f, h1 = 0.f, h2 = 0.f, h3 = 0.f;
#pragma unroll
    for (int j = 0; j < 6; ++j) {
        h0 += xv[j] * w[j];
        h1 += xv[j] * w[6 + j];
        h2 += xv[j] * w[12 + j];
        h3 += xv[j] * w[18 + j];
    }
    Half4 o;
    o.a = __floats2half2_rn(h0 * dinv, h1 * dinv);
    o.b = __floats2half2_rn(h2 * dinv, h3 * dinv);
    ph[i] = o;
    dinvg[i] = dinv;
}

// ---------------- pass 3: bin by SOURCE partition, 4B records (c<<10)|r_local ----------------

__global__ __launch_bounds__(BINB) void k_binS(const int* __restrict__ row,
                                               const int* __restrict__ col, int E,
                                               int P, int cap, int* __restrict__ cursorS,
                                               unsigned* __restrict__ binS) {
    __shared__ unsigned lbuf[EPB];          // 32 KB
    __shared__ int lcount[NPART_MAX];
    __shared__ int lbase[NPART_MAX];
    __shared__ int gbase[NPART_MAX];
    __shared__ int lpos[NPART_MAX];
    __shared__ int sc[NPART_MAX];

    int t = threadIdx.x;
    int start = blockIdx.x * EPB;
    int end = min(start + EPB, E);
    bool full = (end - start) == EPB;

    lcount[t] = 0; lpos[t] = 0;
    __syncthreads();

    if (full) {
        const int4* r4 = (const int4*)(row + start);
#pragma unroll
        for (int i = 0; i < EPB / 4 / BINB; ++i) {
            int4 r = r4[t + i * BINB];
            atomicAdd(&lcount[r.x >> SHIFT], 1);
            atomicAdd(&lcount[r.y >> SHIFT], 1);
            atomicAdd(&lcount[r.z >> SHIFT], 1);
            atomicAdd(&lcount[r.w >> SHIFT], 1);
        }
    } else {
        for (int e = start + t; e < end; e += BINB)
            atomicAdd(&lcount[row[e] >> SHIFT], 1);
    }
    __syncthreads();

    sc[t] = lcount[t];
    __syncthreads();
    for (int off = 1; off < NPART_MAX; off <<= 1) {
        int v = (t >= off) ? sc[t - off] : 0;
        __syncthreads();
        sc[t] += v;
        __syncthreads();
    }
    lbase[t] = sc[t] - lcount[t];
    if (t < P) {
        int c = lcount[t];
        gbase[t] = (c > 0) ? atomicAdd(&cursorS[t], c) : 0;
    }
    __syncthreads();

    if (full) {
        const int4* r4 = (const int4*)(row + start);
        const int4* c4 = (const int4*)(col + start);
#pragma unroll
        for (int i = 0; i < EPB / 4 / BINB; ++i) {
            int4 r = r4[t + i * BINB];
            int4 c = c4[t + i * BINB];
            int part, slot;
            part = r.x >> SHIFT; slot = atomicAdd(&lpos[part], 1);
            lbuf[lbase[part] + slot] = ((unsigned)c.x << SHIFT) | ((unsigned)r.x & MASK);
            part = r.y >> SHIFT; slot = atomicAdd(&lpos[part], 1);
            lbuf[lbase[part] + slot] = ((unsigned)c.y << SHIFT) | ((unsigned)r.y & MASK);
            part = r.z >> SHIFT; slot = atomicAdd(&lpos[part], 1);
            lbuf[lbase[part] + slot] = ((unsigned)c.z << SHIFT) | ((unsigned)r.z & MASK);
            part = r.w >> SHIFT; slot = atomicAdd(&lpos[part], 1);
            lbuf[lbase[part] + slot] = ((unsigned)c.w << SHIFT) | ((unsigned)r.w & MASK);
        }
    } else {
        for (int e = start + t; e < end; e += BINB) {
            int r = row[e], c = col[e];
            int part = r >> SHIFT;
            int slot = atomicAdd(&lpos[part], 1);
            lbuf[lbase[part] + slot] = ((unsigned)c << SHIFT) | ((unsigned)r & MASK);
        }
    }
    __syncthreads();

    int lane = t & 63;
    int wave = t >> 6;
    const int nwaves = BINB / 64;
    for (int part = wave; part < P; part += nwaves) {
        int cnt = lcount[part];
        if (cnt == 0) continue;
        int lb = lbase[part];
        int gb = gbase[part];
        unsigned* dst = binS + (size_t)part * cap;
        for (int j = lane; j < cnt; j += 64) {
            int slot = gb + j;
            if (slot < cap) dst[slot] = lbuf[lb + j];
        }
    }
}

// ---------------- pass 4: attach fp8 values (LDS gather), counting-sort to target bins ----------------

__global__ __launch_bounds__(BINB) void k_attach(const unsigned* __restrict__ binS,
                                                 const int* __restrict__ cursorS, int cap,
                                                 const Half4* __restrict__ ph, int n,
                                                 int P, int* __restrict__ cursorV,
                                                 unsigned* __restrict__ valV,
                                                 unsigned short* __restrict__ clV) {
    __shared__ unsigned pslice[NP];          // 4 KB fp8x4 per node of this source partition
    __shared__ unsigned lbufV[CHMAX];        // 34 KB
    __shared__ unsigned short lbufC[CHMAX];  // 17 KB
    __shared__ int lcount[NPART_MAX];
    __shared__ int lbase[NPART_MAX];
    __shared__ int gbase[NPART_MAX];
    __shared__ int lpos[NPART_MAX];
    __shared__ int sc[NPART_MAX];

    int part = blockIdx.x >> 2;     // SUBA = 4
    int sub = blockIdx.x & 3;
    int t = threadIdx.x;

    // stage fp8 p-slice for this source partition
    int base = part * NP;
    for (int i = t; i < NP; i += BINB) {
        int node = base + i;
        unsigned wv = 0;
        if (node < n) {
            Half4 hp = ph[node];
            float2 pa = __half22float2(hp.a);
            float2 pb = __half22float2(hp.b);
            int w = __builtin_amdgcn_cvt_pk_fp8_f32(pa.x, pa.y, 0, false);
            w = __builtin_amdgcn_cvt_pk_fp8_f32(pb.x, pb.y, w, true);
            wv = (unsigned)w;
        }
        pslice[i] = wv;
    }
    lcount[t] = 0; lpos[t] = 0;
    __syncthreads();

    int cnt = min(cursorS[part], cap);
    int chunk = (cnt + SUBA - 1) / SUBA;
    int s = sub * chunk;
    int e = min(cnt, s + chunk);
    const unsigned* bin = binS + (size_t)part * cap;

    // phase 1: count per target partition
    for (int i = s + t; i < e; i += BINB)
        atomicAdd(&lcount[bin[i] >> 20], 1);
    __syncthreads();

    // phase 2: scan + reserve
    sc[t] = lcount[t];
    __syncthreads();
    for (int off = 1; off < NPART_MAX; off <<= 1) {
        int v = (t >= off) ? sc[t - off] : 0;
        __syncthreads();
        sc[t] += v;
        __syncthreads();
    }
    lbase[t] = sc[t] - lcount[t];
    if (t < P) {
        int c = lcount[t];
        gbase[t] = (c > 0) ? atomicAdd(&cursorV[t], c) : 0;
    }
    __syncthreads();

    // phase 3: place (value from LDS slice, c_local) sorted by target partition
    for (int i = s + t; i < e; i += BINB) {
        unsigned rec = bin[i];
        int tpart = (int)(rec >> 20);
        int slot = lbase[tpart] + atomicAdd(&lpos[tpart], 1);
        lbufV[slot] = pslice[rec & MASK];
        lbufC[slot] = (unsigned short)((rec >> SHIFT) & MASK);
    }
    __syncthreads();

    // phase 4: coalesced flush
    int lane = t & 63;
    int wave = t >> 6;
    const int nwaves = BINB / 64;
    for (int tp = wave; tp < P; tp += nwaves) {
        int c = lcount[tp];
        if (c == 0) continue;
        int lb = lbase[tp];
        int gb = gbase[tp];
        unsigned* dv = valV + (size_t)tp * cap;
        unsigned short* dc = clV + (size_t)tp * cap;
        for (int j = lane; j < c; j += 64) {
            int slot = gb + j;
            if (slot < cap) {
                dv[slot] = lbufV[lb + j];
                dc[slot] = lbufC[lb + j];
            }
        }
    }
}

// ---------------- pass 5: accumulate value records into LDS tile, flush partials ----------------

__global__ __launch_bounds__(BT) void k_accV(const unsigned* __restrict__ valV,
                                             const unsigned short* __restrict__ clV,
                                             const int* __restrict__ cursorV, int cap,
                                             float4* __restrict__ Spart) {
    __shared__ float S[NP * 5];      // stride 5
    int part = blockIdx.x >> 2;      // SUBV = 4
    int sub = blockIdx.x & 3;
    int tid = threadIdx.x;
    for (int i = tid; i < NP * 5; i += BT) S[i] = 0.f;
    __syncthreads();
    int cnt = min(cursorV[part], cap);
    int chunk = (cnt + SUBV - 1) / SUBV;
    int s = sub * chunk;
    int e = min(cnt, s + chunk);
    const unsigned* vp = valV + (size_t)part * cap;
    const unsigned short* cp = clV + (size_t)part * cap;
    for (int i = s + tid; i < e; i += BT) {
        unsigned val = vp[i];
        int cl = cp[i];
        floatx2 lo = __builtin_amdgcn_cvt_pk_f32_fp8((int)val, false);
        floatx2 hi = __builtin_amdgcn_cvt_pk_f32_fp8((int)val, true);
        float* sp = &S[cl * 5];
        unsafeAtomicAdd(sp + 0, lo[0]);
        unsafeAtomicAdd(sp + 1, lo[1]);
        unsafeAtomicAdd(sp + 2, hi[0]);
        unsafeAtomicAdd(sp + 3, hi[1]);
    }
    __syncthreads();
    float4* dst = Spart + (size_t)blockIdx.x * NP;
    for (int k = tid; k < NP; k += BT) {
        float4 o;
        o.x = S[k * 5 + 0]; o.y = S[k * 5 + 1];
        o.z = S[k * 5 + 2]; o.w = S[k * 5 + 3];
        dst[k] = o;
    }
}

// ---------------- pass 6: combine partials + self-loop, tanh, reduce -> gsum ----------------

__global__ __launch_bounds__(BT) void k_tanh(const float4* __restrict__ Spart,
                                             const Half4* __restrict__ ph,
                                             const float* __restrict__ dinvg,
                                             const float* __restrict__ conv_b,
                                             int n, int SUB, float* __restrict__ gsum) {
    int node = blockIdx.x * BT + threadIdx.x;
    float4 acc = {0.f, 0.f, 0.f, 0.f};
    if (node < n) {
        int part = node >> SHIFT;
        int local = node & MASK;
        float4 s = {0.f, 0.f, 0.f, 0.f};
        for (int sub = 0; sub < SUB; ++sub) {
            float4 t = Spart[((size_t)(part * SUB + sub)) * NP + local];
            s.x += t.x; s.y += t.y; s.z += t.z; s.w += t.w;
        }
        float di = dinvg[node];
        Half4 hp = ph[node];
        float2 pa = __half22float2(hp.a), pb = __half22float2(hp.b);
        acc.x = tanhf(di * (s.x + pa.x) + conv_b[0]);
        acc.y = tanhf(di * (s.y + pa.y) + conv_b[1]);
        acc.z = tanhf(di * (s.z + pb.x) + conv_b[2]);
        acc.w = tanhf(di * (s.w + pb.y) + conv_b[3]);
    }
#pragma unroll
    for (int off = 32; off > 0; off >>= 1) {
        acc.x += __shfl_down(acc.x, off);
        acc.y += __shfl_down(acc.y, off);
        acc.z += __shfl_down(acc.z, off);
        acc.w += __shfl_down(acc.w, off);
    }
    __shared__ float4 red[BT / 64];
    int lane = threadIdx.x & 63, wv = threadIdx.x >> 6;
    if (lane == 0) red[wv] = acc;
    __syncthreads();
    if (threadIdx.x == 0) {
        float4 tt = red[0];
        for (int k = 1; k < BT / 64; ++k) {
            tt.x += red[k].x; tt.y += red[k].y; tt.z += red[k].z; tt.w += red[k].w;
        }
        unsafeAtomicAdd(&gsum[0], tt.x);
        unsafeAtomicAdd(&gsum[1], tt.y);
        unsafeAtomicAdd(&gsum[2], tt.z);
        unsafeAtomicAdd(&gsum[3], tt.w);
    }
}

__global__ void k_head(const float* __restrict__ gsum,
                       const float* __restrict__ fc1w, const float* __restrict__ fc1b,
                       const float* __restrict__ fc3w, const float* __restrict__ fc3b,
                       float* __restrict__ out, int n) {
    __shared__ float hdn[64];
    int t = threadIdx.x;
    float g[4];
    float inv_n = 1.0f / (float)n;
#pragma unroll
    for (int j = 0; j < 4; ++j) g[j] = gsum[j] * inv_n;
    if (t < 64) {
        float a = fc1b[t];
#pragma unroll
        for (int j = 0; j < 4; ++j) a += g[j] * fc1w[t * 4 + j];
        hdn[t] = fmaxf(a, 0.f);
    }
    __syncthreads();
    if (t < 10) {
        float a = fc3b[t];
#pragma unroll
        for (int k = 0; k < 64; ++k) a += hdn[k] * fc3w[t * 64 + k];
        out[t] = a;
    }
}

// ---------------- fallback path (R5: single target-binning + global gather) ----------------

__global__ __launch_bounds__(BINB) void k_bin(const int* __restrict__ row,
                                              const int* __restrict__ col, int E,
                                              int P, int cap, int* __restrict__ cursor,
                                              unsigned* __restrict__ binned) {
    __shared__ unsigned lbuf[EPB];
    __shared__ int lcount[NPART_MAX];
    __shared__ int lbase[NPART_MAX];
    __shared__ int gbase[NPART_MAX];
    __shared__ int lpos[NPART_MAX];
    __shared__ int sc[NPART_MAX];

    int t = threadIdx.x;
    int start = blockIdx.x * EPB;
    int end = min(start + EPB, E);
    bool full = (end - start) == EPB;

    lcount[t] = 0; lpos[t] = 0;
    __syncthreads();
    if (full) {
        const int4* c4 = (const int4*)(col + start);
#pragma unroll
        for (int i = 0; i < EPB / 4 / BINB; ++i) {
            int4 c = c4[t + i * BINB];
            atomicAdd(&lcount[c.x >> SHIFT], 1);
            atomicAdd(&lcount[c.y >> SHIFT], 1);
            atomicAdd(&lcount[c.z >> SHIFT], 1);
            atomicAdd(&lcount[c.w >> SHIFT], 1);
        }
    } else {
        for (int e = start + t; e < end; e += BINB)
            atomicAdd(&lcount[col[e] >> SHIFT], 1);
    }
    __syncthreads();
    sc[t] = lcount[t];
    __syncthreads();
    for (int off = 1; off < NPART_MAX; off <<= 1) {
        int v = (t >= off) ? sc[t - off] : 0;
        __syncthreads();
        sc[t] += v;
        __syncthreads();
    }
    lbase[t] = sc[t] - lcount[t];
    if (t < P) {
        int c = lcount[t];
        gbase[t] = (c > 0) ? atomicAdd(&cursor[t], c) : 0;
    }
    __syncthreads();
    if (full) {
        const int4* c4 = (const int4*)(col + start);
        const int4* r4 = (const int4*)(row + start);
#pragma unroll
        for (int i = 0; i < EPB / 4 / BINB; ++i) {
            int4 c = c4[t + i * BINB];
            int4 r = r4[t + i * BINB];
            int part, slot;
            part = c.x >> SHIFT; slot = atomicAdd(&lpos[part], 1);
            lbuf[lbase[part] + slot] = ((unsigned)r.x << SHIFT) | ((unsigned)c.x & MASK);
            part = c.y >> SHIFT; slot = atomicAdd(&lpos[part], 1);
            lbuf[lbase[part] + slot] = ((unsigned)r.y << SHIFT) | ((unsigned)c.y & MASK);
            part = c.z >> SHIFT; slot = atomicAdd(&lpos[part], 1);
            lbuf[lbase[part] + slot] = ((unsigned)r.z << SHIFT) | ((unsigned)c.z & MASK);
            part = c.w >> SHIFT; slot = atomicAdd(&lpos[part], 1);
            lbuf[lbase[part] + slot] = ((unsigned)r.w << SHIFT) | ((unsigned)c.w & MASK);
        }
    } else {
        for (int e = start + t; e < end; e += BINB) {
            int r = row[e], c = col[e];
            int part = c >> SHIFT;
            int slot = atomicAdd(&lpos[part], 1);
            lbuf[lbase[part] + slot] = ((unsigned)r << SHIFT) | ((unsigned)c & MASK);
        }
    }
    __syncthreads();
    int lane = t & 63;
    int wave = t >> 6;
    const int nwaves = BINB / 64;
    for (int part = wave; part < P; part += nwaves) {
        int cnt = lcount[part];
        if (cnt == 0) continue;
        int lb = lbase[part];
        int gb = gbase[part];
        unsigned* dst = binned + (size_t)part * cap;
        for (int j = lane; j < cnt; j += 64) {
            int slot = gb + j;
            if (slot < cap) dst[slot] = lbuf[lb + j];
        }
    }
}

__global__ __launch_bounds__(BT) void k_part_node(const unsigned* __restrict__ binned,
                                                  const int* __restrict__ cursor, int cap,
                                                  const float* __restrict__ x,
                                                  const float* __restrict__ conv_w, int n,
                                                  Half4* __restrict__ ph,
                                                  float* __restrict__ dinvg) {
    __shared__ int degs[NP];
    __shared__ float w[24];
    int part = blockIdx.x;
    int tid = threadIdx.x;
    if (tid < 24) w[tid] = conv_w[tid];
    for (int i = tid; i < NP; i += BT) degs[i] = 0;
    __syncthreads();
    int cnt = min(cursor[part], cap);
    const unsigned* bin = binned + (size_t)part * cap;
    const uint4* bin4 = (const uint4*)bin;
    int cnt4 = cnt >> 2;
    for (int i = tid; i < cnt4; i += BT) {
        uint4 v = bin4[i];
        atomicAdd(&degs[v.x & MASK], 1);
        atomicAdd(&degs[v.y & MASK], 1);
        atomicAdd(&degs[v.z & MASK], 1);
        atomicAdd(&degs[v.w & MASK], 1);
    }
    for (int e = (cnt4 << 2) + tid; e < cnt; e += BT)
        atomicAdd(&degs[bin[e] & MASK], 1);
    __syncthreads();
    int base = part * NP;
    for (int i = tid; i < NP; i += BT) {
        int node = base + i;
        if (node >= n) continue;
        float dinv = rsqrtf((float)(degs[i] + 1));
        const float* xr = x + (size_t)node * 6;
        float2 a = *(const float2*)xr;
        float2 b = *(const float2*)(xr + 2);
        float2 cc = *(const float2*)(xr + 4);
        float xv[6] = {a.x, a.y, b.x, b.y, cc.x, cc.y};
        float h0 = 0.f, h1 = 0.f, h2 = 0.f, h3 = 0.f;
#pragma unroll
        for (int j = 0; j < 6; ++j) {
            h0 += xv[j] * w[j];
            h1 += xv[j] * w[6 + j];
            h2 += xv[j] * w[12 + j];
            h3 += xv[j] * w[18 + j];
        }
        Half4 o;
        o.a = __floats2half2_rn(h0 * dinv, h1 * dinv);
        o.b = __floats2half2_rn(h2 * dinv, h3 * dinv);
        ph[node] = o;
        dinvg[node] = dinv;
    }
}

__device__ __forceinline__ void acc_edge(float* __restrict__ S, unsigned v,
                                         const Half4& h) {
    float2 a = __half22float2(h.a), b = __half22float2(h.b);
    float* s = &S[(v & MASK) * 5];
    unsafeAtomicAdd(s + 0, a.x);
    unsafeAtomicAdd(s + 1, a.y);
    unsafeAtomicAdd(s + 2, b.x);
    unsafeAtomicAdd(s + 3, b.y);
}

__global__ __launch_bounds__(BT) void k_acc2(const unsigned* __restrict__ binned,
                                             const int* __restrict__ cursor, int cap,
                                             const Half4* __restrict__ ph, int SUB,
                                             float4* __restrict__ Spart) {
    __shared__ float S[NP * 5];
    int part = blockIdx.x / SUB;
    int sub = blockIdx.x - part * SUB;
    int tid = threadIdx.x;
    for (int i = tid; i < NP * 5; i += BT) S[i] = 0.f;
    __syncthreads();
    int cnt = min(cursor[part], cap);
    const unsigned* bin = binned + (size_t)part * cap;
    const uint4* bin4 = (const uint4*)bin;
    int cnt4 = cnt >> 2;
    int chunk4 = (cnt4 + SUB - 1) / SUB;
    int s4 = sub * chunk4;
    int e4 = min(cnt4, s4 + chunk4);
    for (int i = s4 + tid; i < e4; i += BT) {
        uint4 v = bin4[i];
        Half4 h0 = ph[v.x >> SHIFT];
        Half4 h1 = ph[v.y >> SHIFT];
        Half4 h2 = ph[v.z >> SHIFT];
        Half4 h3 = ph[v.w >> SHIFT];
        acc_edge(S, v.x, h0); acc_edge(S, v.y, h1);
        acc_edge(S, v.z, h2); acc_edge(S, v.w, h3);
    }
    if (sub == SUB - 1) {
        for (int e = (cnt4 << 2) + tid; e < cnt; e += BT)
            acc_edge(S, bin[e], ph[bin[e] >> SHIFT]);
    }
    __syncthreads();
    float4* dst = Spart + (size_t)blockIdx.x * NP;
    for (int k = tid; k < NP; k += BT) {
        float4 o;
        o.x = S[k * 5 + 0]; o.y = S[k * 5 + 1];
        o.z = S[k * 5 + 2]; o.w = S[k * 5 + 3];
        dst[k] = o;
    }
}

// ---------------- launch ----------------

extern "C" void kernel_launch(void* const* d_in, const int* in_sizes, int n_in,
                              void* d_out, int out_size, void* d_ws, size_t ws_size,
                              hipStream_t stream) {
    const float* x      = (const float*)d_in[0];
    const int*   ei     = (const int*)d_in[1];
    const float* conv_w = (const float*)d_in[2];
    const float* conv_b = (const float*)d_in[3];
    const float* fc1w   = (const float*)d_in[4];
    const float* fc1b   = (const float*)d_in[5];
    const float* fc3w   = (const float*)d_in[6];
    const float* fc3b   = (const float*)d_in[7];

    int n = in_sizes[0] / 6;
    int E = in_sizes[1] / 2;
    const int* row = ei;       // edge_index[0] = source
    const int* col = ei + E;   // edge_index[1] = target

    int P = (n + NP - 1) / NP;
    int avg = (E + P - 1) / P;
    int cap = ((avg + avg / 32 + 256) + 15) & ~15;

    char* ws = (char*)d_ws;
    bool ok = (P <= NPART_MAX) && (n < (1 << 22)) && ((cap + SUBA - 1) / SUBA <= CHMAX);

    // --- new-path layout ---
    size_t off = 0;
    size_t curT_off = off;   off += (size_t)P * sizeof(int);
    size_t curS_off = off;   off += (size_t)P * sizeof(int);
    size_t curV_off = off;   off += (size_t)P * sizeof(int);
    size_t gsum_off = off;   off += 4 * sizeof(float);
    size_t zero_end = off;
    off = (off + 15) & ~(size_t)15;
    size_t dinv_off = off;   off += (size_t)n * sizeof(float);
    off = (off + 15) & ~(size_t)15;
    size_t ph_off = off;     off += (size_t)n * sizeof(Half4);
    off = (off + 15) & ~(size_t)15;
    size_t degp_off = off;   off += (size_t)P * SUBD * NP * sizeof(int);
    off = (off + 15) & ~(size_t)15;
    size_t binT_off = off;   off += (size_t)P * cap * sizeof(unsigned short);
    off = (off + 15) & ~(size_t)15;
    size_t binS_off = off;   off += (size_t)P * cap * sizeof(unsigned);
    off = (off + 15) & ~(size_t)15;
    size_t valV_off = off;   off += (size_t)P * cap * sizeof(unsigned);
    off = (off + 15) & ~(size_t)15;
    size_t clV_off = off;    off += (size_t)P * cap * sizeof(unsigned short);
    off = (off + 255) & ~(size_t)255;
    size_t spart_off = off;  off += (size_t)P * SUBV * NP * sizeof(float4);
    size_t need_new = off;

    if (ok && ws_size >= need_new) {
        int* cursorT = (int*)(ws + curT_off);
        int* cursorS = (int*)(ws + curS_off);
        int* cursorV = (int*)(ws + curV_off);
        float* gsum = (float*)(ws + gsum_off);
        float* dinvg = (float*)(ws + dinv_off);
        Half4* ph = (Half4*)(ws + ph_off);
        int* degpart = (int*)(ws + degp_off);
        unsigned short* binT = (unsigned short*)(ws + binT_off);
        unsigned* binS = (unsigned*)(ws + binS_off);
        unsigned* valV = (unsigned*)(ws + valV_off);
        unsigned short* clV = (unsigned short*)(ws + clV_off);
        float4* Spart = (float4*)(ws + spart_off);

        (void)hipMemsetAsync(d_ws, 0, zero_end, stream);
        int bin_blocks = (E + EPB - 1) / EPB;
        k_binT2<<<bin_blocks, BINB, 0, stream>>>(col, E, P, cap, cursorT, binT);
        k_degS<<<P * SUBD, BT, 0, stream>>>(binT, cursorT, cap, degpart);
        k_node2<<<(n + BT - 1) / BT, BT, 0, stream>>>(degpart, x, conv_w, n, ph, dinvg);
        k_binS<<<bin_blocks, BINB, 0, stream>>>(row, col, E, P, cap, cursorS, binS);
        k_attach<<<P * SUBA, BINB, 0, stream>>>(binS, cursorS, cap, ph, n, P, cursorV, valV, clV);
        k_accV<<<P * SUBV, BT, 0, stream>>>(valV, clV, cursorV, cap, Spart);
        k_tanh<<<(n + BT - 1) / BT, BT, 0, stream>>>(Spart, ph, dinvg, conv_b, n, SUBV, gsum);
        k_head<<<1, 64, 0, stream>>>(gsum, fc1w, fc1b, fc3w, fc3b, (float*)d_out, n);
        return;
    }

    // --- fallback: R5 path ---
    size_t o = 0;
    size_t f_cur = o;        o += (size_t)P * sizeof(int);
    o = (o + 15) & ~(size_t)15;
    size_t f_gsum = o;       o += 4 * sizeof(float);
    size_t f_zero = o + 4 * sizeof(float);
    o = (f_zero + 15) & ~(size_t)15;
    size_t f_dinv = o;       o += (size_t)n * sizeof(float);
    o = (o + 15) & ~(size_t)15;
    size_t f_ph = o;         o += (size_t)n * sizeof(Half4);
    o = (o + 15) & ~(size_t)15;
    size_t f_bin = o;        o += (size_t)P * cap * sizeof(unsigned);
    o = (o + 255) & ~(size_t)255;
    size_t f_spart = o;
    size_t spart1 = (size_t)P * NP * sizeof(float4);

    int SUB = 0;
    if (ok && ws_size >= f_spart + 2 * spart1) SUB = 2;
    else if (ok && ws_size >= f_spart + spart1) SUB = 1;

    if (SUB > 0) {
        int* cursor = (int*)(ws + f_cur);
        float* gsum = (float*)(ws + f_gsum);
        float* dinvg = (float*)(ws + f_dinv);
        Half4* ph = (Half4*)(ws + f_ph);
        unsigned* binned = (unsigned*)(ws + f_bin);
        float4* Spart = (float4*)(ws + f_spart);

        (void)hipMemsetAsync(d_ws, 0, f_zero, stream);
        int bin_blocks = (E + EPB - 1) / EPB;
        k_bin<<<bin_blocks, BINB, 0, stream>>>(row, col, E, P, cap, cursor, binned);
        k_part_node<<<P, BT, 0, stream>>>(binned, cursor, cap, x, conv_w, n, ph, dinvg);
        k_acc2<<<P * SUB, BT, 0, stream>>>(binned, cursor, cap, ph, SUB, Spart);
        k_tanh<<<(n + BT - 1) / BT, BT, 0, stream>>>(Spart, ph, dinvg, conv_b, n, SUB, gsum);
        k_head<<<1, 64, 0, stream>>>(gsum, fc1w, fc1b, fc3w, fc3b, (float*)d_out, n);
    }
}